// Round 4
// baseline (1403.207 us; speedup 1.0000x reference)
//
#include <hip/hip_runtime.h>
#include <hip/hip_bf16.h>

#define B_   1024
#define L_   200
#define H_   128
#define BL_  204800   // B_*L_
#define G3_  384

typedef __bf16 bf16x8 __attribute__((ext_vector_type(8)));
typedef __bf16 bf16x4 __attribute__((ext_vector_type(4)));
typedef float  f32x4  __attribute__((ext_vector_type(4)));

#define LOG2E 1.4426950408889634f

__device__ __forceinline__ float sigf(float x) {
    return __builtin_amdgcn_rcpf(1.f + exp2f(-LOG2E * x));
}
__device__ __forceinline__ float tanh_fast(float x) {
    float e = exp2f(-2.f * LOG2E * x);
    return (1.f - e) * __builtin_amdgcn_rcpf(1.f + e);
}
__device__ __forceinline__ bf16x8 cvt8(float4 a, float4 b) {
    bf16x8 v;
    v[0] = (__bf16)a.x; v[1] = (__bf16)a.y; v[2] = (__bf16)a.z; v[3] = (__bf16)a.w;
    v[4] = (__bf16)b.x; v[5] = (__bf16)b.y; v[6] = (__bf16)b.z; v[7] = (__bf16)b.w;
    return v;
}

// ---------------- K0: sentinel (workspace too small -> distinguishable absmax)
__global__ __launch_bounds__(256) void k_sentinel(float* __restrict__ out, int n) {
    const int i = blockIdx.x * 256 + threadIdx.x;
    if (i < n) out[i] = -5.0f;
}

// ---------------- K1: dec_linear  code[b, j] = received[b,:] . W_lin[j,:] + b_lin[j]
__global__ __launch_bounds__(256) void k_declin(
    const float* __restrict__ rcv, const float* __restrict__ Wl,
    const float* __restrict__ bl, float* __restrict__ code) {
    __shared__ float rs[4][400];
    const int tid = threadIdx.x;
    const int b0 = blockIdx.x * 4;
    for (int i = tid; i < 1600; i += 256) ((float*)rs)[i] = rcv[(size_t)b0 * 400 + i];
    __syncthreads();
    #pragma unroll
    for (int rep = 0; rep < 2; ++rep) {
        const int j = tid + rep * 256;
        if (j < 400) {
            float a0 = 0.f, a1 = 0.f, a2 = 0.f, a3 = 0.f;
            const float4* wp = (const float4*)(Wl + (size_t)j * 400);
            for (int k = 0; k < 100; ++k) {
                float4 w4 = wp[k];
                const int kk = k * 4;
                a0 += w4.x*rs[0][kk] + w4.y*rs[0][kk+1] + w4.z*rs[0][kk+2] + w4.w*rs[0][kk+3];
                a1 += w4.x*rs[1][kk] + w4.y*rs[1][kk+1] + w4.z*rs[1][kk+2] + w4.w*rs[1][kk+3];
                a2 += w4.x*rs[2][kk] + w4.y*rs[2][kk+1] + w4.z*rs[2][kk+2] + w4.w*rs[2][kk+3];
                a3 += w4.x*rs[3][kk] + w4.y*rs[3][kk+1] + w4.z*rs[3][kk+2] + w4.w*rs[3][kk+3];
            }
            const float bb = bl[j];
            code[(size_t)(b0+0)*400 + j] = a0 + bb;
            code[(size_t)(b0+1)*400 + j] = a1 + bb;
            code[(size_t)(b0+2)*400 + j] = a2 + bb;
            code[(size_t)(b0+3)*400 + j] = a3 + bb;
        }
    }
}

// ---------------- K2: layer0 GRU, BOTH dirs fused per block (4 batches, 8 waves).
// Waves 0..3 = forward chain, waves 4..7 = backward chain; independent chains
// interleave on the CU between the shared barriers. 256 blocks = 1 block/CU,
// 2 waves/SIMD.
__global__ __launch_bounds__(512, 2) void k_gru0(
    const float* __restrict__ code,
    const float* __restrict__ Wih_f, const float* __restrict__ Whh_f,
    const float* __restrict__ bih_f, const float* __restrict__ bhh_f,
    const float* __restrict__ Wih_b, const float* __restrict__ Whh_b,
    const float* __restrict__ bih_b, const float* __restrict__ bhh_b,
    __bf16* __restrict__ h0) {
    const int b0 = blockIdx.x * 4;
    const int tid = threadIdx.x;
    const int wa = tid >> 6;           // 0..7
    const int d  = wa >> 2;            // direction
    const int w  = wa & 3;             // wave within dir group
    const int ln = tid & 63, q = ln >> 4, r16 = ln & 15;
    const int ltid = tid & 255;

    const float* Wih = d ? Wih_b : Wih_f;
    const float* Whh = d ? Whh_b : Whh_f;
    const float* bih = d ? bih_b : bih_f;
    const float* bhh = d ? bhh_b : bhh_f;

    __shared__ __bf16 h_bf[2][16][136];   // rows 4..15 zero (MFMA pad)
    __shared__ float  h_f[2][4][132];
    __shared__ float  code_s[4][400];

    for (int i = tid; i < 4 * 400; i += 512) ((float*)code_s)[i] = code[(size_t)b0 * 400 + i];
    for (int i = tid; i < 2 * 16 * 136; i += 512) ((__bf16*)h_bf)[i] = (__bf16)0.f;
    for (int i = tid; i < 2 * 4 * 132; i += 512) ((float*)h_f)[i] = 0.f;

    bf16x8 wfr[2][3][4];
    float wr0[2], wr1[2], wz0[2], wz1[2], wn0[2], wn1[2];
    float xbr[2], xbz[2], xbn[2], bnv[2];
    #pragma unroll
    for (int ci = 0; ci < 2; ++ci) {
        const int jj = (2 * w + ci) * 16 + r16;
        wr0[ci] = Wih[jj * 2];           wr1[ci] = Wih[jj * 2 + 1];
        wz0[ci] = Wih[(jj + 128) * 2];   wz1[ci] = Wih[(jj + 128) * 2 + 1];
        wn0[ci] = Wih[(jj + 256) * 2];   wn1[ci] = Wih[(jj + 256) * 2 + 1];
        xbr[ci] = bih[jj] + bhh[jj];
        xbz[ci] = bih[jj + 128] + bhh[jj + 128];
        xbn[ci] = bih[jj + 256];
        bnv[ci] = bhh[jj + 256];
        #pragma unroll
        for (int g = 0; g < 3; ++g) {
            const int j = ((2 * w + ci) + g * 8) * 16 + r16;
            const float* p = Whh + (size_t)j * H_;
            #pragma unroll
            for (int kt = 0; kt < 4; ++kt) {
                float4 x0 = *(const float4*)(p + kt * 32 + q * 8);
                float4 x1 = *(const float4*)(p + kt * 32 + q * 8 + 4);
                wfr[ci][g][kt] = cvt8(x0, x1);
            }
        }
    }
    __syncthreads();

    for (int t = 0; t < L_; ++t) {
        const int l = d ? (L_ - 1 - t) : t;
        bf16x8 af[4];
        #pragma unroll
        for (int kt = 0; kt < 4; ++kt)
            af[kt] = *(const bf16x8*)&h_bf[d][r16][kt * 32 + q * 8];

        float hn[2][4];
        #pragma unroll
        for (int ci = 0; ci < 2; ++ci) {
            const int jj = (2 * w + ci) * 16 + r16;
            f32x4 ar = {0.f,0.f,0.f,0.f}, az = {0.f,0.f,0.f,0.f}, an = {0.f,0.f,0.f,0.f};
            #pragma unroll
            for (int kt = 0; kt < 4; ++kt) {
                ar = __builtin_amdgcn_mfma_f32_16x16x32_bf16(af[kt], wfr[ci][0][kt], ar, 0, 0, 0);
                az = __builtin_amdgcn_mfma_f32_16x16x32_bf16(af[kt], wfr[ci][1][kt], az, 0, 0, 0);
                an = __builtin_amdgcn_mfma_f32_16x16x32_bf16(af[kt], wfr[ci][2][kt], an, 0, 0, 0);
            }
            if (q == 0) {   // real rows 0..3 only
                #pragma unroll
                for (int reg = 0; reg < 4; ++reg) {
                    const float c0 = code_s[reg][l * 2], c1 = code_s[reg][l * 2 + 1];
                    const float r = sigf(c0 * wr0[ci] + c1 * wr1[ci] + xbr[ci] + ar[reg]);
                    const float z = sigf(c0 * wz0[ci] + c1 * wz1[ci] + xbz[ci] + az[reg]);
                    const float n = tanh_fast(c0 * wn0[ci] + c1 * wn1[ci] + xbn[ci] + r * (an[reg] + bnv[ci]));
                    const float hold = h_f[d][reg][jj];
                    hn[ci][reg] = n + z * (hold - n);
                }
            }
        }
        __syncthreads();   // all reads of h done before writes
        if (q == 0) {
            #pragma unroll
            for (int ci = 0; ci < 2; ++ci) {
                const int jj = (2 * w + ci) * 16 + r16;
                #pragma unroll
                for (int reg = 0; reg < 4; ++reg) {
                    h_f[d][reg][jj] = hn[ci][reg];
                    h_bf[d][reg][jj] = (__bf16)hn[ci][reg];
                }
            }
        }
        __syncthreads();   // writes visible
        if (ltid < 64) {   // each dir group stores its own 4 rows x 128 cols
            const int row = ltid >> 4, cch = ltid & 15;
            bf16x8 v = *(const bf16x8*)&h_bf[d][row][cch * 8];
            *(bf16x8*)&h0[((size_t)(b0 + row) * L_ + l) * 256 + d * 128 + cch * 8] = v;
        }
    }
}

// ---------------- K3: convert Wih1 (both dirs) fp32 -> bf16  [2][384][256]
__global__ __launch_bounds__(256) void k_cvtW(
    const float* __restrict__ Wfp, const float* __restrict__ Wbp,
    __bf16* __restrict__ out) {
    const int j = blockIdx.x * 256 + threadIdx.x;   // 0..49151
    const int base = j * 4;
    const int dir = base >= 98304;
    const int idx = dir ? base - 98304 : base;
    float4 v = *(const float4*)((dir ? Wbp : Wfp) + idx);
    bf16x4 o;
    o[0] = (__bf16)v.x; o[1] = (__bf16)v.y; o[2] = (__bf16)v.z; o[3] = (__bf16)v.w;
    *(bf16x4*)&out[base] = o;
}

// ---- producer helpers for k_gru1f (chunk = 4 steps, tile = 8 batches) ----
__device__ __forceinline__ void load_afr(
    const __bf16* __restrict__ h0, int P, int dir, int b0, int q, int r16,
    bf16x8 (&afr)[2][8]) {
    #pragma unroll
    for (int m = 0; m < 2; ++m) {
        const int row = m * 16 + r16;
        const int sp = row >> 3, bt = row & 7;       // chunk row = sp*8 + bt
        const int t = P * 4 + sp;
        const int l = dir ? (L_ - 1 - t) : t;
        const __bf16* hp = h0 + ((size_t)(b0 + bt) * L_ + l) * 256 + q * 8;
        #pragma unroll
        for (int k8 = 0; k8 < 8; ++k8)
            afr[m][k8] = *(const bf16x8*)(hp + k8 * 32);
    }
}

__device__ __forceinline__ void gemm_col(
    const __bf16* __restrict__ Wbase, int n, int pw, int q, int r16,
    const bf16x8 (&afr)[2][8], __bf16 (*xgT)[36]) {
    const __bf16* wp = Wbase + (size_t)n * 16 * 256;
    f32x4 a0 = {0.f,0.f,0.f,0.f}, a1 = {0.f,0.f,0.f,0.f};
    #pragma unroll
    for (int k8 = 0; k8 < 8; ++k8) {
        const bf16x8 bfrag = *(const bf16x8*)(wp + k8 * 32);
        a0 = __builtin_amdgcn_mfma_f32_16x16x32_bf16(afr[0][k8], bfrag, a0, 0, 0, 0);
        a1 = __builtin_amdgcn_mfma_f32_16x16x32_bf16(afr[1][k8], bfrag, a1, 0, 0, 0);
    }
    const int col = pw * 96 + n * 16 + r16;
    bf16x4 o0, o1;
    o0[0] = (__bf16)a0[0]; o0[1] = (__bf16)a0[1]; o0[2] = (__bf16)a0[2]; o0[3] = (__bf16)a0[3];
    o1[0] = (__bf16)a1[0]; o1[1] = (__bf16)a1[1]; o1[2] = (__bf16)a1[2]; o1[3] = (__bf16)a1[3];
    *(bf16x4*)&xgT[col][q * 4]      = o0;   // chunk rows 0..15
    *(bf16x4*)&xgT[col][16 + q * 4] = o1;   // chunk rows 16..31
}

// ---------------- K4: layer1 GRU, producer-consumer wave split.
// 512 threads: waves 0..3 consume (recurrence, 2 cols x 16 each), waves 4..7
// produce next chunk's xg = h0 @ Wih1^T into double-buffered LDS, sliced
// between the step barriers. 256 blocks = 1 block/CU, 2 waves/SIMD.
__global__ __launch_bounds__(512, 2) void k_gru1f(
    const __bf16* __restrict__ h0,       // [B][L][256]
    const __bf16* __restrict__ Wihbf,    // [2][384][256] bf16
    const float* __restrict__ bih_f, const float* __restrict__ bhh_f,
    const float* __restrict__ bih_b, const float* __restrict__ bhh_b,
    const float* __restrict__ Whh_f, const float* __restrict__ Whh_b,
    const float* __restrict__ Wfin,
    float* __restrict__ partial) {
    const int dir = blockIdx.y;
    const int b0 = blockIdx.x * 8;
    const float* Whh = dir ? Whh_b : Whh_f;
    const float* bih = dir ? bih_b : bih_f;
    const float* bhh = dir ? bhh_b : bhh_f;
    const __bf16* Wb = Wihbf + (size_t)dir * 384 * 256;

    const int tid = threadIdx.x;
    const int w = tid >> 6, ln = tid & 63, q = ln >> 4, r16 = ln & 15;
    const bool prod = (w >= 4);
    const int pw = w & 3;

    __shared__ __bf16 xgT[2][384][36];   // 55,296 B  [buf][col][chunk row s*8+bt]
    __shared__ __bf16 h_bf[16][136];     //  4,352 B  (rows 8..15 zero pad)
    __shared__ float  h_f[8][132];       //  4,224 B
    __shared__ float  wacc[4][8];        //    128 B  -> total 64,000 B

    for (int i = tid; i < 16 * 136; i += 512) ((__bf16*)h_bf)[i] = (__bf16)0.f;
    for (int i = tid; i < 8 * 132; i += 512) ((float*)h_f)[i] = 0.f;

    // consumer-only constants (registers)
    bf16x8 wfr[2][3][4];
    float xbr[2], xbz[2], xbn[2], bnv[2], wfv[2];
    if (!prod) {
        #pragma unroll
        for (int ci = 0; ci < 2; ++ci) {
            const int jj = (2 * w + ci) * 16 + r16;
            xbr[ci] = bih[jj] + bhh[jj];
            xbz[ci] = bih[jj + 128] + bhh[jj + 128];
            xbn[ci] = bih[jj + 256];
            bnv[ci] = bhh[jj + 256];
            wfv[ci] = Wfin[dir * 128 + jj];
            #pragma unroll
            for (int g = 0; g < 3; ++g) {
                const int j = ((2 * w + ci) + g * 8) * 16 + r16;
                const float* p = Whh + (size_t)j * H_;
                #pragma unroll
                for (int kt = 0; kt < 4; ++kt) {
                    float4 x0 = *(const float4*)(p + kt * 32 + q * 8);
                    float4 x1 = *(const float4*)(p + kt * 32 + q * 8 + 4);
                    wfr[ci][g][kt] = cvt8(x0, x1);
                }
            }
        }
    }
    const __bf16* Wbase = Wb + (size_t)(pw * 96 + r16) * 256 + q * 8;

    bf16x8 afr[2][8];
    if (prod) {   // prologue: chunk 0 into buffer 0 (consumers wait once)
        load_afr(h0, 0, dir, b0, q, r16, afr);
        #pragma unroll
        for (int n = 0; n < 6; ++n) gemm_col(Wbase, n, pw, q, r16, afr, xgT[0]);
    }
    __syncthreads();

    for (int c = 0; c < 50; ++c) {
        const int cb = c & 1, nb = cb ^ 1;
        const bool pv = prod && (c + 1 < 50);
        #pragma unroll
        for (int s = 0; s < 4; ++s) {
            // ---- producer slice for chunk c+1 (runs while consumers compute)
            if (pv) {
                if (s == 0) {
                    load_afr(h0, c + 1, dir, b0, q, r16, afr);
                    gemm_col(Wbase, 0, pw, q, r16, afr, xgT[nb]);
                } else if (s == 1) {
                    gemm_col(Wbase, 1, pw, q, r16, afr, xgT[nb]);
                    gemm_col(Wbase, 2, pw, q, r16, afr, xgT[nb]);
                } else if (s == 2) {
                    gemm_col(Wbase, 3, pw, q, r16, afr, xgT[nb]);
                    gemm_col(Wbase, 4, pw, q, r16, afr, xgT[nb]);
                } else {
                    gemm_col(Wbase, 5, pw, q, r16, afr, xgT[nb]);
                }
            }
            // ---- consumer step
            const int t = c * 4 + s;
            const int l = dir ? (L_ - 1 - t) : t;
            float hn[2][4];
            float pacc[4] = {0.f, 0.f, 0.f, 0.f};
            if (!prod) {
                bf16x8 af[4];
                #pragma unroll
                for (int kt = 0; kt < 4; ++kt)
                    af[kt] = *(const bf16x8*)&h_bf[r16][kt * 32 + q * 8];
                #pragma unroll
                for (int ci = 0; ci < 2; ++ci) {
                    const int jj = (2 * w + ci) * 16 + r16;
                    f32x4 ar = {0.f,0.f,0.f,0.f}, az = {0.f,0.f,0.f,0.f}, an = {0.f,0.f,0.f,0.f};
                    #pragma unroll
                    for (int kt = 0; kt < 4; ++kt) {
                        ar = __builtin_amdgcn_mfma_f32_16x16x32_bf16(af[kt], wfr[ci][0][kt], ar, 0, 0, 0);
                        az = __builtin_amdgcn_mfma_f32_16x16x32_bf16(af[kt], wfr[ci][1][kt], az, 0, 0, 0);
                        an = __builtin_amdgcn_mfma_f32_16x16x32_bf16(af[kt], wfr[ci][2][kt], an, 0, 0, 0);
                    }
                    if (q < 2) {   // real rows 0..7
                        bf16x4 xr4 = *(const bf16x4*)&xgT[cb][jj      ][s * 8 + q * 4];
                        bf16x4 xz4 = *(const bf16x4*)&xgT[cb][jj + 128][s * 8 + q * 4];
                        bf16x4 xn4 = *(const bf16x4*)&xgT[cb][jj + 256][s * 8 + q * 4];
                        #pragma unroll
                        for (int reg = 0; reg < 4; ++reg) {
                            const int m = q * 4 + reg;
                            const float r = sigf((float)xr4[reg] + xbr[ci] + ar[reg]);
                            const float z = sigf((float)xz4[reg] + xbz[ci] + az[reg]);
                            const float n = tanh_fast((float)xn4[reg] + xbn[ci] + r * (an[reg] + bnv[ci]));
                            const float hold = h_f[m][jj];
                            const float hv = n + z * (hold - n);
                            hn[ci][reg] = hv;
                            pacc[reg] += hv * wfv[ci];
                        }
                    }
                }
            }
            __syncthreads();   // barrier A: h/xgT reads done
            if (!prod && q < 2) {
                #pragma unroll
                for (int ci = 0; ci < 2; ++ci) {
                    const int jj = (2 * w + ci) * 16 + r16;
                    #pragma unroll
                    for (int reg = 0; reg < 4; ++reg) {
                        const int m = q * 4 + reg;
                        h_f[m][jj] = hn[ci][reg];
                        h_bf[m][jj] = (__bf16)hn[ci][reg];
                    }
                }
                #pragma unroll
                for (int reg = 0; reg < 4; ++reg) {
                    float v = pacc[reg];
                    v += __shfl_xor(v, 1); v += __shfl_xor(v, 2);
                    v += __shfl_xor(v, 4); v += __shfl_xor(v, 8);
                    if (r16 == 0) wacc[w][q * 4 + reg] = v;
                }
            }
            __syncthreads();   // barrier B: h writes + wacc visible
            if (tid < 8) {
                const float v = wacc[0][tid] + wacc[1][tid] + wacc[2][tid] + wacc[3][tid];
                partial[(size_t)dir * BL_ + (size_t)(b0 + tid) * L_ + l] = v;
            }
        }
    }
}

// ---------------- K5: out = sigmoid(pf + pb + bf)
__global__ __launch_bounds__(256) void k_final(
    const float* __restrict__ partial, const float* __restrict__ bfp,
    float* __restrict__ out) {
    const int i = blockIdx.x * 256 + threadIdx.x;
    if (i < BL_) out[i] = sigf(partial[i] + partial[BL_ + i] + bfp[0]);
}

extern "C" void kernel_launch(void* const* d_in, const int* in_sizes, int n_in,
                              void* d_out, int out_size, void* d_ws, size_t ws_size,
                              hipStream_t stream) {
    const float* rcv   = (const float*)d_in[0];
    const float* Wl    = (const float*)d_in[1];
    const float* bl    = (const float*)d_in[2];
    const float* Wih0f = (const float*)d_in[3];
    const float* Whh0f = (const float*)d_in[4];
    const float* bih0f = (const float*)d_in[5];
    const float* bhh0f = (const float*)d_in[6];
    const float* Wih0b = (const float*)d_in[7];
    const float* Whh0b = (const float*)d_in[8];
    const float* bih0b = (const float*)d_in[9];
    const float* bhh0b = (const float*)d_in[10];
    const float* Wih1f = (const float*)d_in[11];
    const float* Whh1f = (const float*)d_in[12];
    const float* bih1f = (const float*)d_in[13];
    const float* bhh1f = (const float*)d_in[14];
    const float* Wih1b = (const float*)d_in[15];
    const float* Whh1b = (const float*)d_in[16];
    const float* bih1b = (const float*)d_in[17];
    const float* bhh1b = (const float*)d_in[18];
    const float* Wfin  = (const float*)d_in[19];
    const float* bfin  = (const float*)d_in[20];

    const size_t OFF_CODE = 0;                     // 1,638,400 B
    const size_t OFF_PART = 1638400;               // 1,638,400 B
    const size_t OFF_H0   = 3276800;               // 104,857,600 B
    const size_t OFF_WBF  = 108134400;             //     393,216 B
    const size_t WS_NEEDED = 108527616;            // ~103.5 MB total

    if (ws_size < WS_NEEDED) {
        k_sentinel<<<(out_size + 255) / 256, 256, 0, stream>>>((float*)d_out, out_size);
        return;
    }

    char* ws = (char*)d_ws;
    float*  code    = (float*)(ws + OFF_CODE);
    float*  partial = (float*)(ws + OFF_PART);
    __bf16* h0      = (__bf16*)(ws + OFF_H0);
    __bf16* Wihbf   = (__bf16*)(ws + OFF_WBF);

    k_declin<<<256, 256, 0, stream>>>(rcv, Wl, bl, code);
    k_cvtW<<<192, 256, 0, stream>>>(Wih1f, Wih1b, Wihbf);
    k_gru0<<<256, 512, 0, stream>>>(code, Wih0f, Whh0f, bih0f, bhh0f,
                                    Wih0b, Whh0b, bih0b, bhh0b, h0);
    k_gru1f<<<dim3(128, 2), 512, 0, stream>>>(h0, Wihbf,
                                              bih1f, bhh1f, bih1b, bhh1b,
                                              Whh1f, Whh1b, Wfin, partial);
    k_final<<<800, 256, 0, stream>>>(partial, bfin, (float*)d_out);
}

// Round 5
// 790.042 us; speedup vs baseline: 1.7761x; 1.7761x over previous
//
#include <hip/hip_runtime.h>
#include <hip/hip_bf16.h>

#define B_   1024
#define L_   200
#define H_   128
#define BL_  204800   // B_*L_
#define G3_  384

typedef __bf16 bf16x8 __attribute__((ext_vector_type(8)));
typedef __bf16 bf16x4 __attribute__((ext_vector_type(4)));
typedef float  f32x4  __attribute__((ext_vector_type(4)));

__device__ __forceinline__ float sigf(float x) {
    return __builtin_amdgcn_rcpf(1.f + __expf(-x));
}
__device__ __forceinline__ float tanh_fast(float x) {
    float e = __expf(-2.f * x);
    return (1.f - e) * __builtin_amdgcn_rcpf(1.f + e);
}
__device__ __forceinline__ bf16x8 cvt8(float4 a, float4 b) {
    bf16x8 v;
    v[0] = (__bf16)a.x; v[1] = (__bf16)a.y; v[2] = (__bf16)a.z; v[3] = (__bf16)a.w;
    v[4] = (__bf16)b.x; v[5] = (__bf16)b.y; v[6] = (__bf16)b.z; v[7] = (__bf16)b.w;
    return v;
}

// ---------------- K0: sentinel (workspace too small -> distinguishable absmax)
__global__ __launch_bounds__(256) void k_sentinel(float* __restrict__ out, int n) {
    const int i = blockIdx.x * 256 + threadIdx.x;
    if (i < n) out[i] = -5.0f;
}

// ---------------- K1: dec_linear
__global__ __launch_bounds__(256) void k_declin(
    const float* __restrict__ rcv, const float* __restrict__ Wl,
    const float* __restrict__ bl, float* __restrict__ code) {
    __shared__ float rs[4][400];
    const int tid = threadIdx.x;
    const int b0 = blockIdx.x * 4;
    for (int i = tid; i < 1600; i += 256) ((float*)rs)[i] = rcv[(size_t)b0 * 400 + i];
    __syncthreads();
    #pragma unroll
    for (int rep = 0; rep < 2; ++rep) {
        const int j = tid + rep * 256;
        if (j < 400) {
            float a0 = 0.f, a1 = 0.f, a2 = 0.f, a3 = 0.f;
            const float4* wp = (const float4*)(Wl + (size_t)j * 400);
            for (int k = 0; k < 100; ++k) {
                float4 w4 = wp[k];
                const int kk = k * 4;
                a0 += w4.x*rs[0][kk] + w4.y*rs[0][kk+1] + w4.z*rs[0][kk+2] + w4.w*rs[0][kk+3];
                a1 += w4.x*rs[1][kk] + w4.y*rs[1][kk+1] + w4.z*rs[1][kk+2] + w4.w*rs[1][kk+3];
                a2 += w4.x*rs[2][kk] + w4.y*rs[2][kk+1] + w4.z*rs[2][kk+2] + w4.w*rs[2][kk+3];
                a3 += w4.x*rs[3][kk] + w4.y*rs[3][kk+1] + w4.z*rs[3][kk+2] + w4.w*rs[3][kk+3];
            }
            const float bb = bl[j];
            code[(size_t)(b0+0)*400 + j] = a0 + bb;
            code[(size_t)(b0+1)*400 + j] = a1 + bb;
            code[(size_t)(b0+2)*400 + j] = a2 + bb;
            code[(size_t)(b0+3)*400 + j] = a3 + bb;
        }
    }
}

// ---------------- K2: layer0 GRU, tile=8, ONE barrier per step, h double-buffered.
__global__ __launch_bounds__(256) void k_gru0(
    const float* __restrict__ code,
    const float* __restrict__ Wih_f, const float* __restrict__ Whh_f,
    const float* __restrict__ bih_f, const float* __restrict__ bhh_f,
    const float* __restrict__ Wih_b, const float* __restrict__ Whh_b,
    const float* __restrict__ bih_b, const float* __restrict__ bhh_b,
    __bf16* __restrict__ h0) {
    const int dir = blockIdx.y;
    const int b0 = blockIdx.x * 8;
    const float* Wih = dir ? Wih_b : Wih_f;
    const float* Whh = dir ? Whh_b : Whh_f;
    const float* bih = dir ? bih_b : bih_f;
    const float* bhh = dir ? bhh_b : bhh_f;

    const int tid = threadIdx.x;
    const int w = tid >> 6, ln = tid & 63, q = ln >> 4, r16 = ln & 15;

    __shared__ __bf16 h_bf[2][16][136];   // rows 8..15 zero (MFMA pad); double-buffered
    __shared__ float  code_s[8][400];

    for (int i = tid; i < 8 * 400; i += 256) ((float*)code_s)[i] = code[(size_t)b0 * 400 + i];
    for (int i = tid; i < 2 * 16 * 136; i += 256) ((__bf16*)h_bf)[i] = (__bf16)0.f;

    // per-lane gate constants + Whh B-fragments in registers
    bf16x8 wfr[2][3][4];
    float wr0[2], wr1[2], wz0[2], wz1[2], wn0[2], wn1[2];
    float xbr[2], xbz[2], xbn[2], bnv[2];
    float hreg[2][4];   // fp32 h carried in registers (lane owns fixed (m,jj))
    #pragma unroll
    for (int ci = 0; ci < 2; ++ci) {
        const int jj = (2 * w + ci) * 16 + r16;
        wr0[ci] = Wih[jj * 2];           wr1[ci] = Wih[jj * 2 + 1];
        wz0[ci] = Wih[(jj + 128) * 2];   wz1[ci] = Wih[(jj + 128) * 2 + 1];
        wn0[ci] = Wih[(jj + 256) * 2];   wn1[ci] = Wih[(jj + 256) * 2 + 1];
        xbr[ci] = bih[jj] + bhh[jj];
        xbz[ci] = bih[jj + 128] + bhh[jj + 128];
        xbn[ci] = bih[jj + 256];
        bnv[ci] = bhh[jj + 256];
        #pragma unroll
        for (int reg = 0; reg < 4; ++reg) hreg[ci][reg] = 0.f;
        #pragma unroll
        for (int g = 0; g < 3; ++g) {
            const int j = ((2 * w + ci) + g * 8) * 16 + r16;
            const float* p = Whh + (size_t)j * H_;
            #pragma unroll
            for (int kt = 0; kt < 4; ++kt) {
                float4 x0 = *(const float4*)(p + kt * 32 + q * 8);
                float4 x1 = *(const float4*)(p + kt * 32 + q * 8 + 4);
                wfr[ci][g][kt] = cvt8(x0, x1);
            }
        }
    }
    __syncthreads();

    for (int t = 0; t < L_; ++t) {
        const int cur = t & 1, nxt = cur ^ 1;
        // store h_{t-1} (made visible by last barrier) — drains during this step
        if (t > 0 && tid < 128) {
            const int lp = dir ? (L_ - t) : (t - 1);
            const int row = tid >> 4, cch = tid & 15;
            bf16x8 v = *(const bf16x8*)&h_bf[cur][row][cch * 8];
            *(bf16x8*)&h0[((size_t)(b0 + row) * L_ + lp) * 256 + dir * 128 + cch * 8] = v;
        }
        const int l = dir ? (L_ - 1 - t) : t;
        bf16x8 af[4];
        #pragma unroll
        for (int kt = 0; kt < 4; ++kt)
            af[kt] = *(const bf16x8*)&h_bf[cur][r16][kt * 32 + q * 8];

        #pragma unroll
        for (int ci = 0; ci < 2; ++ci) {
            const int jj = (2 * w + ci) * 16 + r16;
            f32x4 ar = {0.f,0.f,0.f,0.f}, az = {0.f,0.f,0.f,0.f}, an = {0.f,0.f,0.f,0.f};
            #pragma unroll
            for (int kt = 0; kt < 4; ++kt) {
                ar = __builtin_amdgcn_mfma_f32_16x16x32_bf16(af[kt], wfr[ci][0][kt], ar, 0, 0, 0);
                az = __builtin_amdgcn_mfma_f32_16x16x32_bf16(af[kt], wfr[ci][1][kt], az, 0, 0, 0);
                an = __builtin_amdgcn_mfma_f32_16x16x32_bf16(af[kt], wfr[ci][2][kt], an, 0, 0, 0);
            }
            if (q < 2) {   // real rows 0..7
                #pragma unroll
                for (int reg = 0; reg < 4; ++reg) {
                    const int m = q * 4 + reg;
                    const float c0 = code_s[m][l * 2], c1 = code_s[m][l * 2 + 1];
                    const float r = sigf(c0 * wr0[ci] + c1 * wr1[ci] + xbr[ci] + ar[reg]);
                    const float z = sigf(c0 * wz0[ci] + c1 * wz1[ci] + xbz[ci] + az[reg]);
                    const float n = tanh_fast(c0 * wn0[ci] + c1 * wn1[ci] + xbn[ci] + r * (an[reg] + bnv[ci]));
                    const float hv = n + z * (hreg[ci][reg] - n);
                    hreg[ci][reg] = hv;
                    h_bf[nxt][m][jj] = (__bf16)hv;
                }
            }
        }
        __syncthreads();   // single barrier: h[nxt] visible for next step
    }
    // final step's h (t=199) lives in buf[200&1 ^ ... ] = buf[0^...]: buf[(L_)&1]
    if (tid < 128) {
        const int lp = dir ? 0 : (L_ - 1);
        const int row = tid >> 4, cch = tid & 15;
        bf16x8 v = *(const bf16x8*)&h_bf[L_ & 1][row][cch * 8];
        *(bf16x8*)&h0[((size_t)(b0 + row) * L_ + lp) * 256 + dir * 128 + cch * 8] = v;
    }
}

// ---------------- K3: convert Wih1 (both dirs) fp32 -> bf16  [2][384][256]
__global__ __launch_bounds__(256) void k_cvtW(
    const float* __restrict__ Wfp, const float* __restrict__ Wbp,
    __bf16* __restrict__ out) {
    const int j = blockIdx.x * 256 + threadIdx.x;
    const int base = j * 4;
    const int dir = base >= 98304;
    const int idx = dir ? base - 98304 : base;
    float4 v = *(const float4*)((dir ? Wbp : Wfp) + idx);
    bf16x4 o;
    o[0] = (__bf16)v.x; o[1] = (__bf16)v.y; o[2] = (__bf16)v.z; o[3] = (__bf16)v.w;
    *(bf16x4*)&out[base] = o;
}

// ---------------- K4: layer1 GRU, tile=8, in-line chunk GEMM (8 steps/chunk),
// ONE barrier per step, h double-buffered, fused final-linear dot.
__global__ __launch_bounds__(256) void k_gru1f(
    const __bf16* __restrict__ h0,       // [B][L][256]
    const __bf16* __restrict__ Wihbf,    // [2][384][256] bf16
    const float* __restrict__ bih_f, const float* __restrict__ bhh_f,
    const float* __restrict__ bih_b, const float* __restrict__ bhh_b,
    const float* __restrict__ Whh_f, const float* __restrict__ Whh_b,
    const float* __restrict__ Wfin,
    float* __restrict__ partial) {
    const int dir = blockIdx.y;
    const int b0 = blockIdx.x * 8;
    const float* Whh = dir ? Whh_b : Whh_f;
    const float* bih = dir ? bih_b : bih_f;
    const float* bhh = dir ? bhh_b : bhh_f;
    const __bf16* Wb = Wihbf + (size_t)dir * 384 * 256;

    const int tid = threadIdx.x;
    const int w = tid >> 6, ln = tid & 63, q = ln >> 4, r16 = ln & 15;

    __shared__ __bf16 xgT[384][68];      // 52,224 B [col][chunk row = s*8+bt]
    __shared__ __bf16 h_bf[2][16][136];  //  8,704 B (rows 8..15 zero pad)
    __shared__ float  wacc[2][4][8];     //    256 B (step-parity double buffer)
                                         // total 61,184 B

    for (int i = tid; i < 2 * 16 * 136; i += 256) ((__bf16*)h_bf)[i] = (__bf16)0.f;

    bf16x8 wfr[2][3][4];
    float xbr[2], xbz[2], xbn[2], bnv[2], wfv[2];
    float hreg[2][4];
    #pragma unroll
    for (int ci = 0; ci < 2; ++ci) {
        const int jj = (2 * w + ci) * 16 + r16;
        xbr[ci] = bih[jj] + bhh[jj];
        xbz[ci] = bih[jj + 128] + bhh[jj + 128];
        xbn[ci] = bih[jj + 256];
        bnv[ci] = bhh[jj + 256];
        wfv[ci] = Wfin[dir * 128 + jj];
        #pragma unroll
        for (int reg = 0; reg < 4; ++reg) hreg[ci][reg] = 0.f;
        #pragma unroll
        for (int g = 0; g < 3; ++g) {
            const int j = ((2 * w + ci) + g * 8) * 16 + r16;
            const float* p = Whh + (size_t)j * H_;
            #pragma unroll
            for (int kt = 0; kt < 4; ++kt) {
                float4 x0 = *(const float4*)(p + kt * 32 + q * 8);
                float4 x1 = *(const float4*)(p + kt * 32 + q * 8 + 4);
                wfr[ci][g][kt] = cvt8(x0, x1);
            }
        }
    }
    __syncthreads();

    int gstep = 0;   // global step counter for h_bf parity
    for (int c = 0; c < 25; ++c) {
        // ---- chunk GEMM: xg[64 x 384] = h0_chunk @ Wih1^T (prev chunk's last
        // barrier separates these writes from the prior reads)
        bf16x8 afr[4][8];
        #pragma unroll
        for (int m = 0; m < 4; ++m) {
            const int row = m * 16 + r16;
            const int s = row >> 3, bt = row & 7;
            const int t = c * 8 + s;
            const int l = dir ? (L_ - 1 - t) : t;
            const __bf16* hp = h0 + ((size_t)(b0 + bt) * L_ + l) * 256 + q * 8;
            #pragma unroll
            for (int k8 = 0; k8 < 8; ++k8)
                afr[m][k8] = *(const bf16x8*)(hp + k8 * 32);
        }
        const __bf16* Wbase = Wb + (size_t)(w * 96 + r16) * 256 + q * 8;
        #pragma unroll
        for (int n = 0; n < 6; ++n) {
            const __bf16* wp = Wbase + (size_t)n * 16 * 256;
            f32x4 acc[4];
            #pragma unroll
            for (int m = 0; m < 4; ++m) { acc[m][0]=0.f; acc[m][1]=0.f; acc[m][2]=0.f; acc[m][3]=0.f; }
            #pragma unroll
            for (int k8 = 0; k8 < 8; ++k8) {
                const bf16x8 bfrag = *(const bf16x8*)(wp + k8 * 32);
                #pragma unroll
                for (int m = 0; m < 4; ++m)
                    acc[m] = __builtin_amdgcn_mfma_f32_16x16x32_bf16(afr[m][k8], bfrag, acc[m], 0, 0, 0);
            }
            const int col = w * 96 + n * 16 + r16;
            #pragma unroll
            for (int m = 0; m < 4; ++m) {
                bf16x4 o;
                o[0] = (__bf16)acc[m][0]; o[1] = (__bf16)acc[m][1];
                o[2] = (__bf16)acc[m][2]; o[3] = (__bf16)acc[m][3];
                *(bf16x4*)&xgT[col][m * 16 + q * 4] = o;
            }
        }
        __syncthreads();   // xgT ready

        // ---- 8 recurrent steps, one barrier each
        for (int s = 0; s < 8; ++s, ++gstep) {
            const int cur = gstep & 1, nxt = cur ^ 1;
            const int par = s & 1;
            const int t = c * 8 + s;
            const int l = dir ? (L_ - 1 - t) : t;

            bf16x8 af[4];
            #pragma unroll
            for (int kt = 0; kt < 4; ++kt)
                af[kt] = *(const bf16x8*)&h_bf[cur][r16][kt * 32 + q * 8];

            #pragma unroll
            for (int ci = 0; ci < 2; ++ci) {
                const int jj = (2 * w + ci) * 16 + r16;
                f32x4 ar = {0.f,0.f,0.f,0.f}, az = {0.f,0.f,0.f,0.f}, an = {0.f,0.f,0.f,0.f};
                #pragma unroll
                for (int kt = 0; kt < 4; ++kt) {
                    ar = __builtin_amdgcn_mfma_f32_16x16x32_bf16(af[kt], wfr[ci][0][kt], ar, 0, 0, 0);
                    az = __builtin_amdgcn_mfma_f32_16x16x32_bf16(af[kt], wfr[ci][1][kt], az, 0, 0, 0);
                    an = __builtin_amdgcn_mfma_f32_16x16x32_bf16(af[kt], wfr[ci][2][kt], an, 0, 0, 0);
                }
                if (q < 2) {   // real rows 0..7
                    bf16x4 xr4 = *(const bf16x4*)&xgT[jj      ][s * 8 + q * 4];
                    bf16x4 xz4 = *(const bf16x4*)&xgT[jj + 128][s * 8 + q * 4];
                    bf16x4 xn4 = *(const bf16x4*)&xgT[jj + 256][s * 8 + q * 4];
                    float pacc = 0.f;
                    #pragma unroll
                    for (int reg = 0; reg < 4; ++reg) {
                        const int m = q * 4 + reg;
                        const float r = sigf((float)xr4[reg] + xbr[ci] + ar[reg]);
                        const float z = sigf((float)xz4[reg] + xbz[ci] + az[reg]);
                        const float n = tanh_fast((float)xn4[reg] + xbn[ci] + r * (an[reg] + bnv[ci]));
                        const float hv = n + z * (hreg[ci][reg] - n);
                        hreg[ci][reg] = hv;
                        h_bf[nxt][m][jj] = (__bf16)hv;
                    }
                    (void)pacc;
                }
            }
            // fused final-linear partial dot: sum over jj of hv*wfv, per row m
            if (q < 2) {
                #pragma unroll
                for (int reg = 0; reg < 4; ++reg) {
                    float v = hreg[0][reg] * wfv[0] + hreg[1][reg] * wfv[1];
                    v += __shfl_xor(v, 1); v += __shfl_xor(v, 2);
                    v += __shfl_xor(v, 4); v += __shfl_xor(v, 8);
                    if (r16 == 0) wacc[par][w][q * 4 + reg] = v;
                }
            }
            __syncthreads();   // single barrier: h[nxt] + wacc[par] visible
            if (tid < 8) {     // store drains during next step's compute
                const float v = wacc[par][0][tid] + wacc[par][1][tid]
                              + wacc[par][2][tid] + wacc[par][3][tid];
                partial[(size_t)dir * BL_ + (size_t)(b0 + tid) * L_ + l] = v;
            }
        }
    }
}

// ---------------- K5: out = sigmoid(pf + pb + bf)
__global__ __launch_bounds__(256) void k_final(
    const float* __restrict__ partial, const float* __restrict__ bfp,
    float* __restrict__ out) {
    const int i = blockIdx.x * 256 + threadIdx.x;
    if (i < BL_) out[i] = sigf(partial[i] + partial[BL_ + i] + bfp[0]);
}

extern "C" void kernel_launch(void* const* d_in, const int* in_sizes, int n_in,
                              void* d_out, int out_size, void* d_ws, size_t ws_size,
                              hipStream_t stream) {
    const float* rcv   = (const float*)d_in[0];
    const float* Wl    = (const float*)d_in[1];
    const float* bl    = (const float*)d_in[2];
    const float* Wih0f = (const float*)d_in[3];
    const float* Whh0f = (const float*)d_in[4];
    const float* bih0f = (const float*)d_in[5];
    const float* bhh0f = (const float*)d_in[6];
    const float* Wih0b = (const float*)d_in[7];
    const float* Whh0b = (const float*)d_in[8];
    const float* bih0b = (const float*)d_in[9];
    const float* bhh0b = (const float*)d_in[10];
    const float* Wih1f = (const float*)d_in[11];
    const float* Whh1f = (const float*)d_in[12];
    const float* bih1f = (const float*)d_in[13];
    const float* bhh1f = (const float*)d_in[14];
    const float* Wih1b = (const float*)d_in[15];
    const float* Whh1b = (const float*)d_in[16];
    const float* bih1b = (const float*)d_in[17];
    const float* bhh1b = (const float*)d_in[18];
    const float* Wfin  = (const float*)d_in[19];
    const float* bfin  = (const float*)d_in[20];

    const size_t OFF_CODE = 0;                     // 1,638,400 B
    const size_t OFF_PART = 1638400;               // 1,638,400 B
    const size_t OFF_H0   = 3276800;               // 104,857,600 B
    const size_t OFF_WBF  = 108134400;             //     393,216 B
    const size_t WS_NEEDED = 108527616;            // ~103.5 MB total

    if (ws_size < WS_NEEDED) {
        k_sentinel<<<(out_size + 255) / 256, 256, 0, stream>>>((float*)d_out, out_size);
        return;
    }

    char* ws = (char*)d_ws;
    float*  code    = (float*)(ws + OFF_CODE);
    float*  partial = (float*)(ws + OFF_PART);
    __bf16* h0      = (__bf16*)(ws + OFF_H0);
    __bf16* Wihbf   = (__bf16*)(ws + OFF_WBF);

    k_declin<<<256, 256, 0, stream>>>(rcv, Wl, bl, code);
    k_cvtW<<<192, 256, 0, stream>>>(Wih1f, Wih1b, Wihbf);
    k_gru0<<<dim3(128, 2), 256, 0, stream>>>(code, Wih0f, Whh0f, bih0f, bhh0f,
                                             Wih0b, Whh0b, bih0b, bhh0b, h0);
    k_gru1f<<<dim3(128, 2), 256, 0, stream>>>(h0, Wihbf,
                                              bih1f, bhh1f, bih1b, bhh1b,
                                              Whh1f, Whh1b, Wfin, partial);
    k_final<<<800, 256, 0, stream>>>(partial, bfin, (float*)d_out);
}